// Round 4
// baseline (14306.239 us; speedup 1.0000x reference)
//
#include <hip/hip_runtime.h>
#include <stdint.h>

#define NNODES 2048
#define T_SEQ  2048
#define HD     640
#define GD     2560   // 4*HD
#define KIN    8500
#define NEDGE  65536
#define NGRAPH 16
#define SB     64     // blocks per layer
#define SDP    10     // h-dims per block
#define GATEW  1      // wave that computes gates / produces h
#define REC64  256    // u64 per timestep row: 64 records x 4 parts

typedef unsigned long long u64;

// ---------------------------------------------------------------------------
// Generic C[M,N] = A[M,K] @ W[N,K]^T + b1[n] + b2[n]   (fp32, 64x64x16 tile)
// ---------------------------------------------------------------------------
__global__ __launch_bounds__(256) void gemm_abt(
    const float* __restrict__ A, const float* __restrict__ W,
    const float* __restrict__ b1, const float* __restrict__ b2,
    float* __restrict__ C, int M, int N, int K) {
  __shared__ float As[16][64];
  __shared__ float Ws[16][64];
  const int tid = threadIdx.x;
  const int bm = blockIdx.y * 64, bn = blockIdx.x * 64;
  const int lr = tid >> 2;
  const int lc4 = (tid & 3) << 2;
  const int ty = tid >> 4, tx = tid & 15;
  float acc[4][4] = {};
  const long lK = K;
  for (int k0 = 0; k0 < K; k0 += 16) {
    float a0=0.f,a1=0.f,a2=0.f,a3=0.f, w0=0.f,w1=0.f,w2=0.f,w3=0.f;
    const int ka = k0 + lc4;
    const float* Ap = A + (long)(bm + lr) * lK;
    const float* Wp = W + (long)(bn + lr) * lK;
    if (ka + 3 < K) {
      float4 av = *(const float4*)(Ap + ka);
      float4 wv = *(const float4*)(Wp + ka);
      a0=av.x; a1=av.y; a2=av.z; a3=av.w;
      w0=wv.x; w1=wv.y; w2=wv.z; w3=wv.w;
    } else {
      if (ka     < K) { a0 = Ap[ka];   w0 = Wp[ka];   }
      if (ka + 1 < K) { a1 = Ap[ka+1]; w1 = Wp[ka+1]; }
      if (ka + 2 < K) { a2 = Ap[ka+2]; w2 = Wp[ka+2]; }
    }
    __syncthreads();
    As[lc4+0][lr]=a0; As[lc4+1][lr]=a1; As[lc4+2][lr]=a2; As[lc4+3][lr]=a3;
    Ws[lc4+0][lr]=w0; Ws[lc4+1][lr]=w1; Ws[lc4+2][lr]=w2; Ws[lc4+3][lr]=w3;
    __syncthreads();
#pragma unroll
    for (int kk = 0; kk < 16; kk++) {
      float4 a4 = *(const float4*)&As[kk][ty<<2];
      float4 w4 = *(const float4*)&Ws[kk][tx<<2];
      float avv[4] = {a4.x,a4.y,a4.z,a4.w};
      float wvv[4] = {w4.x,w4.y,w4.z,w4.w};
#pragma unroll
      for (int i = 0; i < 4; i++)
#pragma unroll
        for (int j = 0; j < 4; j++)
          acc[i][j] = fmaf(avv[i], wvv[j], acc[i][j]);
    }
  }
#pragma unroll
  for (int i = 0; i < 4; i++) {
    const int m = bm + (ty<<2) + i;
#pragma unroll
    for (int j = 0; j < 4; j++) {
      const int n = bn + (tx<<2) + j;
      C[(long)m * N + n] = acc[i][j] + b1[n] + b2[n];
    }
  }
}

// ---------------------------------------------------------------------------
// Fused 3-layer pipelined LSTM scan — self-validating 8B record parts.
// Record (32B) for block b at step t: 4 parts; part j = {bf16 h[3j], h[3j+1],
// h[3j+2], u16 seq=t+1} (j=3: only h9, rest 0). Detection == data.
// ---------------------------------------------------------------------------
__device__ __forceinline__ unsigned f2bf(float x) {
  unsigned u = __float_as_uint(x);
  return (u + 0x7fffu + ((u >> 16) & 1u)) >> 16;
}
__device__ __forceinline__ float bf2f(unsigned lo16) {
  return __uint_as_float(lo16 << 16);
}
__device__ __forceinline__ float bfdot(unsigned u, float2 h, float acc) {
  acc = fmaf(h.x, __uint_as_float(u << 16), acc);
  acc = fmaf(h.y, __uint_as_float(u & 0xffff0000u), acc);
  return acc;
}

// Poll `nq` quads (16 records each) of record row `src`; expect seq `exp`;
// skip record `skiprec` (own block; its h goes to LDS via the gate wave).
__device__ __forceinline__ void poll_quads(
    const u64* __restrict__ src, float* __restrict__ dst,
    int lane, int q0, int nq, unsigned exp, int skiprec) {
  const int rsub = lane >> 2, j = lane & 3;
  unsigned pend = (1u << nq) - 1u;
#pragma unroll
  for (int q = 0; q < 4; q++)
    if (q < nq && (q0 + q) * 16 + rsub == skiprec) pend &= ~(1u << q);
  long spins = 0;
  u64 v[4];
  while (__any(pend != 0)) {
#pragma unroll
    for (int q = 0; q < 4; q++)
      if (q < nq && (pend & (1u << q)))
        v[q] = __hip_atomic_load(src + (long)(q0 + q) * 64 + lane,
                                 __ATOMIC_RELAXED, __HIP_MEMORY_SCOPE_AGENT);
#pragma unroll
    for (int q = 0; q < 4; q++)
      if (q < nq && (pend & (1u << q)) && (unsigned)(v[q] >> 48) == exp) {
        pend &= ~(1u << q);
        const int base = ((q0 + q) * 16 + rsub) * SDP + 3 * j;
        const unsigned lo = (unsigned)v[q], hi = (unsigned)(v[q] >> 32);
        dst[base] = bf2f(lo & 0xFFFFu);
        if (j < 3) {
          dst[base + 1] = bf2f(lo >> 16);
          dst[base + 2] = bf2f(hi & 0xFFFFu);
        }
      }
    if (__any(pend != 0)) {
      if (++spins > 30000000L) break;  // safety: wrong > hung
      __builtin_amdgcn_s_sleep(1);
    }
  }
}

__device__ __forceinline__ void zero_row(float* dst, int lane, int q0, int nq) {
  const int rsub = lane >> 2, j = lane & 3;
  for (int q = 0; q < nq; q++) {
    const int base = ((q0 + q) * 16 + rsub) * SDP + 3 * j;
    dst[base] = 0.f;
    if (j < 3) { dst[base + 1] = 0.f; dst[base + 2] = 0.f; }
  }
}

__global__ __launch_bounds__(256, 1) void fused_scan(
    const float* __restrict__ xp,
    const float* __restrict__ whh0,
    const float* __restrict__ wih1, const float* __restrict__ whh1,
    const float* __restrict__ bih1, const float* __restrict__ bhh1,
    const float* __restrict__ wih2, const float* __restrict__ whh2,
    const float* __restrict__ bih2, const float* __restrict__ bhh2,
    u64* __restrict__ rec0, u64* __restrict__ rec1, u64* __restrict__ rec2,
    float* __restrict__ hs2) {
  __shared__ uint4    w4[2][40 * 64];
  __shared__ unsigned w1s[2][40 * 64];
  __shared__ __align__(16) float hbuf[640];
  __shared__ __align__(16) float xbuf[640];
  __shared__ float gdot[40];
  const int tid = threadIdx.x;
  const int l = blockIdx.x / SB, b = blockIdx.x % SB;
  const int lane = tid & 63, wv = tid >> 6;

  const float* Wih = (l == 1) ? wih1 : wih2;
  const float* Whh = (l == 0) ? whh0 : ((l == 1) ? whh1 : whh2);
  const u64* recI = (l == 1) ? rec0 : rec1;     // input records (l>0)
  u64* recO = (l == 0) ? rec0 : ((l == 1) ? rec1 : rec2);

  // stage weight slices -> LDS bf16
  for (int idx = tid; idx < 40 * 64; idx += 256) {
    const int r = idx >> 6, ln = idx & 63;
    const int g = r / SDP, d = r - g * SDP;
    const long grow = (long)(g * HD + b * SDP + d) * HD;
    unsigned um[5];
    const float* wr = Whh + grow;
#pragma unroll
    for (int m = 0; m < 5; m++) {
      float2 wp = *(const float2*)(wr + 2 * (ln + 64 * m));
      um[m] = f2bf(wp.x) | (f2bf(wp.y) << 16);
    }
    w4[1][idx] = make_uint4(um[0], um[1], um[2], um[3]);
    w1s[1][idx] = um[4];
    if (l > 0) {
      const float* wr2 = Wih + grow;
#pragma unroll
      for (int m = 0; m < 5; m++) {
        float2 wp = *(const float2*)(wr2 + 2 * (ln + 64 * m));
        um[m] = f2bf(wp.x) | (f2bf(wp.y) << 16);
      }
      w4[0][idx] = make_uint4(um[0], um[1], um[2], um[3]);
      w1s[0][idx] = um[4];
    }
  }

  // gate-wave external term: xp (l==0, refreshed per step) or bias sum (l>0),
  // held in registers of lanes 0..39 of wave GATEW; shuffled at gate time.
  float ext = 0.f;
  int gxi = 0;
  if (wv == GATEW && lane < 40) {
    const int g = lane / SDP, d = lane - g * SDP;
    gxi = g * HD + b * SDP + d;
    if (l == 0) {
      ext = xp[gxi];   // t = 0
    } else {
      const float* bi = (l == 1) ? bih1 : bih2;
      const float* bh = (l == 1) ? bhh1 : bhh2;
      ext = bi[gxi] + bh[gxi];
    }
  }
  __syncthreads();

  float creg = 0.f;
  for (int t = 0; t < T_SEQ; t++) {
    // ---- poll phase: w0/w2 own-layer h row (t-1); w3 upstream row (t)
    if (wv == 0) {
      if (t == 0) zero_row(hbuf, lane, 0, 2);
      else poll_quads(recO + (long)(t - 1) * REC64, hbuf, lane, 0, 2, (unsigned)t, b);
    } else if (wv == 2) {
      if (t == 0) zero_row(hbuf, lane, 2, 2);
      else poll_quads(recO + (long)(t - 1) * REC64, hbuf, lane, 2, 2, (unsigned)t, b);
    } else if (wv == 3 && l > 0) {
      poll_quads(recI + (long)t * REC64, xbuf, lane, 0, 4, (unsigned)(t + 1), -1);
    }
    __syncthreads();   // A: hbuf/xbuf ready

    // ---- dot phase: wave wv = gate, 10 rows each
    float2 hv[5], xv[5];
#pragma unroll
    for (int m = 0; m < 5; m++) hv[m] = ((const float2*)hbuf)[lane + 64 * m];
    if (l > 0) {
#pragma unroll
      for (int m = 0; m < 5; m++) xv[m] = ((const float2*)xbuf)[lane + 64 * m];
    }
#pragma unroll
    for (int d = 0; d < SDP; d++) {
      const int r = wv * SDP + d;
      const uint4 a = w4[1][r * 64 + lane];
      const unsigned a4 = w1s[1][r * 64 + lane];
      float p = 0.f;
      p = bfdot(a.x, hv[0], p); p = bfdot(a.y, hv[1], p);
      p = bfdot(a.z, hv[2], p); p = bfdot(a.w, hv[3], p);
      p = bfdot(a4,  hv[4], p);
      if (l > 0) {
        const uint4 c = w4[0][r * 64 + lane];
        const unsigned c4 = w1s[0][r * 64 + lane];
        p = bfdot(c.x, xv[0], p); p = bfdot(c.y, xv[1], p);
        p = bfdot(c.z, xv[2], p); p = bfdot(c.w, xv[3], p);
        p = bfdot(c4,  xv[4], p);
      }
#pragma unroll
      for (int off = 32; off; off >>= 1) p += __shfl_down(p, off, 64);
      if (lane == 0) gdot[r] = p;
    }
    __syncthreads();   // B: gdot ready; hbuf/xbuf consumed

    // ---- gate phase (wave GATEW)
    if (wv == GATEW) {
      const float e0 = __shfl(ext, lane);
      const float e1 = __shfl(ext, 10 + lane);
      const float e2 = __shfl(ext, 20 + lane);
      const float e3 = __shfl(ext, 30 + lane);
      float h = 0.f;
      if (lane < SDP) {
        const float gi = e0 + gdot[lane];
        const float gf = e1 + gdot[SDP + lane];
        const float gg = e2 + gdot[2 * SDP + lane];
        const float go = e3 + gdot[3 * SDP + lane];
        const float si = 1.f / (1.f + expf(-gi));
        const float sf = 1.f / (1.f + expf(-gf));
        const float so = 1.f / (1.f + expf(-go));
        creg = sf * creg + si * tanhf(gg);
        h = so * tanhf(creg);
        hbuf[b * SDP + lane] = h;                       // own slice for t+1
        if (l == 2) hs2[(long)t * HD + b * SDP + lane] = h;
      }
      // prefetch next xp (l==0); result used at next step's shuffles
      float extn = ext;
      if (l == 0 && lane < 40 && t + 1 < T_SEQ)
        extn = xp[(long)(t + 1) * GD + gxi];
      // pack + publish record (lanes 0-3, one 32B coalesced store)
      const float ha = __shfl(h, 3 * lane);
      const float hb = __shfl(h, 3 * lane + 1);
      const float hc = __shfl(h, 3 * lane + 2);
      if (lane < 4) {
        const unsigned seq = (unsigned)(t + 1);
        const unsigned sa = f2bf(ha);
        const unsigned sb = (lane < 3) ? f2bf(hb) : 0u;
        const unsigned sc = (lane < 3) ? f2bf(hc) : 0u;
        const u64 val = (u64)(sa | (sb << 16)) | ((u64)(sc | (seq << 16)) << 32);
        __hip_atomic_store(recO + (long)t * REC64 + b * 4 + lane, val,
                           __ATOMIC_RELAXED, __HIP_MEMORY_SCOPE_AGENT);
      }
      ext = extn;
    }
  }
}

// ---------------------------------------------------------------------------
// GCN pieces
// ---------------------------------------------------------------------------
__global__ __launch_bounds__(256) void gcn_gemm(
    const float* __restrict__ X, const float* __restrict__ W,
    float* __restrict__ Y, int di, int dout) {
  __shared__ float xr[640];
  const int n = blockIdx.x;
  for (int k = threadIdx.x; k < di; k += 256) xr[k] = X[(long)n * di + k];
  __syncthreads();
  for (int c = threadIdx.x; c < dout; c += 256) {
    float acc = 0.f;
    for (int k = 0; k < di; k++) acc = fmaf(xr[k], W[(long)k * dout + c], acc);
    Y[(long)n * dout + c] = acc;
  }
}

__global__ void deg_kernel(const int* __restrict__ dst, unsigned int* __restrict__ deg) {
  const int e = blockIdx.x * 256 + threadIdx.x;
  if (e < NEDGE) atomicAdd(&deg[dst[e]], 1u);
}

__global__ void dinv_kernel(const unsigned int* __restrict__ deg, float* __restrict__ dinv) {
  const int n = blockIdx.x * 256 + threadIdx.x;
  if (n < NNODES) dinv[n] = 1.f / sqrtf((float)(deg[n] + 1u));
}

__global__ __launch_bounds__(128) void gcn_scatter(
    const float* __restrict__ XW, const int* __restrict__ src,
    const int* __restrict__ dst, const float* __restrict__ dinv,
    float* __restrict__ out, int dout) {
  const int e = blockIdx.x;
  const int s = src[e], d = dst[e];
  const float nrm = dinv[s] * dinv[d];
  for (int c = threadIdx.x; c < dout; c += 128)
    atomicAdd(&out[(long)d * dout + c], XW[(long)s * dout + c] * nrm);
}

__global__ __launch_bounds__(256) void gcn_bn(
    const float* __restrict__ scat, const float* __restrict__ xw,
    const float* __restrict__ dinv, const float* __restrict__ bias,
    float* __restrict__ out, int dout) {
  const int c = blockIdx.x;
  const float bc = bias[c];
  float s = 0.f, s2 = 0.f;
  for (int n = threadIdx.x; n < NNODES; n += 256) {
    float v = scat[(long)n * dout + c] + xw[(long)n * dout + c] * dinv[n] * dinv[n] + bc;
    v = v >= 0.f ? v : 0.01f * v;
    s += v; s2 += v * v;
  }
  __shared__ float rs[4], rs2[4];
#pragma unroll
  for (int off = 32; off; off >>= 1) { s += __shfl_down(s, off, 64); s2 += __shfl_down(s2, off, 64); }
  const int w = threadIdx.x >> 6;
  if ((threadIdx.x & 63) == 0) { rs[w] = s; rs2[w] = s2; }
  __syncthreads();
  const float ts  = rs[0] + rs[1] + rs[2] + rs[3];
  const float ts2 = rs2[0] + rs2[1] + rs2[2] + rs2[3];
  const float mu = ts * (1.f / (float)NNODES);
  const float var = ts2 * (1.f / (float)NNODES) - mu * mu;
  const float rstd = 1.f / sqrtf(var + 1e-5f);
  for (int n = threadIdx.x; n < NNODES; n += 256) {
    float v = scat[(long)n * dout + c] + xw[(long)n * dout + c] * dinv[n] * dinv[n] + bc;
    v = v >= 0.f ? v : 0.01f * v;
    out[(long)n * dout + c] = (v - mu) * rstd;
  }
}

__global__ __launch_bounds__(64) void pool_kernel(
    const float* __restrict__ x, float* __restrict__ emb, float* __restrict__ dout) {
  const int g = blockIdx.x, c = threadIdx.x;
  if (c >= 50) return;
  float s = 0.f;
  for (int r = 0; r < 128; r++) s += x[(long)(g * 128 + r) * 50 + c];
  emb[g * 50 + c] = s;
  dout[16 + g * 50 + c] = s;
}

__global__ __launch_bounds__(64) void fc_head(
    const float* __restrict__ emb,
    const float* __restrict__ w1, const float* __restrict__ b1,
    const float* __restrict__ w2, const float* __restrict__ b2,
    const float* __restrict__ w3, const float* __restrict__ b3,
    float* __restrict__ dout) {
  const int g = threadIdx.x;
  if (g >= NGRAPH) return;
  float e[50];
#pragma unroll
  for (int k = 0; k < 50; k++) e[k] = emb[g * 50 + k];
  float t1[32];
  for (int j = 0; j < 32; j++) {
    float a = b1[j];
    for (int k = 0; k < 50; k++) a = fmaf(e[k], w1[k * 32 + j], a);
    t1[j] = a;
  }
  float t2[16];
  for (int j = 0; j < 16; j++) {
    float a = b2[j];
    for (int k = 0; k < 32; k++) a = fmaf(t1[k], w2[k * 16 + j], a);
    t2[j] = a;
  }
  float y = b3[0];
  for (int k = 0; k < 16; k++) y = fmaf(t2[k], w3[k], y);
  dout[g] = y;
}

// ---------------------------------------------------------------------------
extern "C" void kernel_launch(void* const* d_in, const int* in_sizes, int n_in,
                              void* d_out, int out_size, void* d_ws, size_t ws_size,
                              hipStream_t stream) {
  const float* x_in  = (const float*)d_in[0];
  const int*   eidx  = (const int*)d_in[1];
  const float* w_ih[3] = {(const float*)d_in[2], (const float*)d_in[6],  (const float*)d_in[10]};
  const float* w_hh[3] = {(const float*)d_in[3], (const float*)d_in[7],  (const float*)d_in[11]};
  const float* b_ih[3] = {(const float*)d_in[4], (const float*)d_in[8],  (const float*)d_in[12]};
  const float* b_hh[3] = {(const float*)d_in[5], (const float*)d_in[9],  (const float*)d_in[13]};
  const float* gw[4] = {(const float*)d_in[14], (const float*)d_in[16], (const float*)d_in[18], (const float*)d_in[20]};
  const float* gbv[4] = {(const float*)d_in[15], (const float*)d_in[17], (const float*)d_in[19], (const float*)d_in[21]};
  const float* fw1 = (const float*)d_in[22]; const float* fb1 = (const float*)d_in[23];
  const float* fw2 = (const float*)d_in[24]; const float* fb2 = (const float*)d_in[25];
  const float* fw3 = (const float*)d_in[26]; const float* fb3 = (const float*)d_in[27];
  const int* src = eidx;
  const int* dst = eidx + NEDGE;

  // workspace layout
  float* ws  = (float*)d_ws;
  float* xp  = ws;                                  // 5,242,880 f
  u64* rec0 = (u64*)(ws + 5242880);                 // 524,288 u64 each
  u64* rec1 = rec0 + 524288;
  u64* rec2 = rec1 + 524288;
  float* hs2 = ws + 5242880 + 3145728;              // 1,310,720 f
  unsigned int* deg = (unsigned int*)(hs2 + 1310720);
  float* dinv = (float*)(deg + 2048);
  float* emb  = dinv + 2048;
  // GCN buffers alias the (then-dead) xp region
  float* ga = xp;
  float* gb = xp + 655360;
  float* x0 = xp + 1310720;
  float* x1 = xp + 1966080;

  // seq=0 in all records (expected seqs are >=1); zero deg
  hipMemsetAsync(rec0, 0, (size_t)3 * 524288 * sizeof(u64), stream);
  hipMemsetAsync(deg, 0, 2048 * sizeof(unsigned int), stream);

  gemm_abt<<<dim3(GD / 64, NNODES / 64), 256, 0, stream>>>(
      x_in, w_ih[0], b_ih[0], b_hh[0], xp, NNODES, GD, KIN);

  deg_kernel<<<NEDGE / 256, 256, 0, stream>>>(dst, deg);
  dinv_kernel<<<NNODES / 256, 256, 0, stream>>>(deg, dinv);

  fused_scan<<<3 * SB, 256, 0, stream>>>(
      xp, w_hh[0], w_ih[1], w_hh[1], b_ih[1], b_hh[1],
      w_ih[2], w_hh[2], b_ih[2], b_hh[2], rec0, rec1, rec2, hs2);

  const int dims_in[4]  = {640, 320, 180, 90};
  const int dims_out[4] = {320, 180, 90, 50};
  const float* xin_l[4] = {hs2, x0, x1, x0};
  float* xout_l[4]      = {x0, x1, x0, x1};
  for (int l = 0; l < 4; l++) {
    gcn_gemm<<<NNODES, 256, 0, stream>>>(xin_l[l], gw[l], ga, dims_in[l], dims_out[l]);
    hipMemsetAsync(gb, 0, (size_t)NNODES * dims_out[l] * sizeof(float), stream);
    gcn_scatter<<<NEDGE, 128, 0, stream>>>(ga, src, dst, dinv, gb, dims_out[l]);
    gcn_bn<<<dims_out[l], 256, 0, stream>>>(gb, ga, dinv, gbv[l], xout_l[l], dims_out[l]);
  }

  pool_kernel<<<NGRAPH, 64, 0, stream>>>(x1, emb, (float*)d_out);
  fc_head<<<1, 64, 0, stream>>>(emb, fw1, fb1, fw2, fb2, fw3, fb3, (float*)d_out);
}

// Round 5
// 8098.913 us; speedup vs baseline: 1.7664x; 1.7664x over previous
//
#include <hip/hip_runtime.h>
#include <stdint.h>

#define NNODES 2048
#define T_SEQ  2048
#define HD     640
#define GD     2560   // 4*HD
#define KIN    8500
#define NEDGE  65536
#define NGRAPH 16
#define SB     64     // blocks per layer
#define SDP    10     // h-dims per block
#define GATEW  1      // wave that computes gates / produces h
#define REC64  256    // u64 per timestep row: 64 records x 4 parts

typedef unsigned long long u64;
typedef _Float16 half2v __attribute__((ext_vector_type(2)));

#if __has_builtin(__builtin_amdgcn_fdot2)
#define HAVE_FDOT2 1
#endif

__device__ __forceinline__ float dot2acc(unsigned w, unsigned h, float acc) {
#ifdef HAVE_FDOT2
  return __builtin_amdgcn_fdot2(__builtin_bit_cast(half2v, w),
                                __builtin_bit_cast(half2v, h), acc, false);
#else
  acc += (float)__builtin_bit_cast(_Float16, (unsigned short)(w & 0xffffu)) *
         (float)__builtin_bit_cast(_Float16, (unsigned short)(h & 0xffffu));
  acc += (float)__builtin_bit_cast(_Float16, (unsigned short)(w >> 16)) *
         (float)__builtin_bit_cast(_Float16, (unsigned short)(h >> 16));
  return acc;
#endif
}

__device__ __forceinline__ unsigned short f2h(float x) {
  return __builtin_bit_cast(unsigned short, (_Float16)x);
}
__device__ __forceinline__ unsigned packh(float a, float b) {
  return (unsigned)f2h(a) | ((unsigned)f2h(b) << 16);
}

// ---------------------------------------------------------------------------
// Generic C[M,N] = A[M,K] @ W[N,K]^T + b1[n] + b2[n]   (fp32, 64x64x16 tile)
// ---------------------------------------------------------------------------
__global__ __launch_bounds__(256) void gemm_abt(
    const float* __restrict__ A, const float* __restrict__ W,
    const float* __restrict__ b1, const float* __restrict__ b2,
    float* __restrict__ C, int M, int N, int K) {
  __shared__ float As[16][64];
  __shared__ float Ws[16][64];
  const int tid = threadIdx.x;
  const int bm = blockIdx.y * 64, bn = blockIdx.x * 64;
  const int lr = tid >> 2;
  const int lc4 = (tid & 3) << 2;
  const int ty = tid >> 4, tx = tid & 15;
  float acc[4][4] = {};
  const long lK = K;
  for (int k0 = 0; k0 < K; k0 += 16) {
    float a0=0.f,a1=0.f,a2=0.f,a3=0.f, w0=0.f,w1=0.f,w2=0.f,w3=0.f;
    const int ka = k0 + lc4;
    const float* Ap = A + (long)(bm + lr) * lK;
    const float* Wp = W + (long)(bn + lr) * lK;
    if (ka + 3 < K) {
      float4 av = *(const float4*)(Ap + ka);
      float4 wv = *(const float4*)(Wp + ka);
      a0=av.x; a1=av.y; a2=av.z; a3=av.w;
      w0=wv.x; w1=wv.y; w2=wv.z; w3=wv.w;
    } else {
      if (ka     < K) { a0 = Ap[ka];   w0 = Wp[ka];   }
      if (ka + 1 < K) { a1 = Ap[ka+1]; w1 = Wp[ka+1]; }
      if (ka + 2 < K) { a2 = Ap[ka+2]; w2 = Wp[ka+2]; }
    }
    __syncthreads();
    As[lc4+0][lr]=a0; As[lc4+1][lr]=a1; As[lc4+2][lr]=a2; As[lc4+3][lr]=a3;
    Ws[lc4+0][lr]=w0; Ws[lc4+1][lr]=w1; Ws[lc4+2][lr]=w2; Ws[lc4+3][lr]=w3;
    __syncthreads();
#pragma unroll
    for (int kk = 0; kk < 16; kk++) {
      float4 a4 = *(const float4*)&As[kk][ty<<2];
      float4 w4 = *(const float4*)&Ws[kk][tx<<2];
      float avv[4] = {a4.x,a4.y,a4.z,a4.w};
      float wvv[4] = {w4.x,w4.y,w4.z,w4.w};
#pragma unroll
      for (int i = 0; i < 4; i++)
#pragma unroll
        for (int j = 0; j < 4; j++)
          acc[i][j] = fmaf(avv[i], wvv[j], acc[i][j]);
    }
  }
#pragma unroll
  for (int i = 0; i < 4; i++) {
    const int m = bm + (ty<<2) + i;
#pragma unroll
    for (int j = 0; j < 4; j++) {
      const int n = bn + (tx<<2) + j;
      C[(long)m * N + n] = acc[i][j] + b1[n] + b2[n];
    }
  }
}

// ---------------------------------------------------------------------------
// Fused 3-layer pipelined LSTM scan — lane-private dot accumulation (no
// shuffle reductions on the recurrence path), f16 weights/h, v_dot2 inner op.
// Record (32B) for block b at step t: 4 parts; part j = {f16 h[3j], h[3j+1],
// h[3j+2], u16 seq=t+1} (j=3: only h9). Detection == data.
// ---------------------------------------------------------------------------
// Poll `nq` quads (16 records each) of record row `src`; expect seq `exp`;
// skip record `skiprec`; unpack detected parts straight into f16 LDS array.
__device__ __forceinline__ void poll_quads(
    const u64* __restrict__ src, unsigned short* __restrict__ dst,
    int lane, int q0, int nq, unsigned exp, int skiprec) {
  const int rsub = lane >> 2, j = lane & 3;
  unsigned pend = (1u << nq) - 1u;
#pragma unroll
  for (int q = 0; q < 4; q++)
    if (q < nq && (q0 + q) * 16 + rsub == skiprec) pend &= ~(1u << q);
  long spins = 0;
  u64 v[4];
  while (__any(pend != 0)) {
#pragma unroll
    for (int q = 0; q < 4; q++)
      if (q < nq && (pend & (1u << q)))
        v[q] = __hip_atomic_load(src + (long)(q0 + q) * 64 + lane,
                                 __ATOMIC_RELAXED, __HIP_MEMORY_SCOPE_AGENT);
#pragma unroll
    for (int q = 0; q < 4; q++)
      if (q < nq && (pend & (1u << q)) && (unsigned)(v[q] >> 48) == exp) {
        pend &= ~(1u << q);
        const int base = ((q0 + q) * 16 + rsub) * SDP + 3 * j;
        const unsigned lo = (unsigned)v[q], hi = (unsigned)(v[q] >> 32);
        dst[base] = (unsigned short)(lo & 0xFFFFu);
        if (j < 3) {
          dst[base + 1] = (unsigned short)(lo >> 16);
          dst[base + 2] = (unsigned short)(hi & 0xFFFFu);
        }
      }
    if (__any(pend != 0)) {
      if (++spins > 30000000L) break;  // safety: wrong > hung
      __builtin_amdgcn_s_sleep(1);
    }
  }
}

__device__ __forceinline__ void zero_row(unsigned short* dst, int lane,
                                         int q0, int nq) {
  const int rsub = lane >> 2, j = lane & 3;
  for (int q = 0; q < nq; q++) {
    const int base = ((q0 + q) * 16 + rsub) * SDP + 3 * j;
    dst[base] = 0;
    if (j < 3) { dst[base + 1] = 0; dst[base + 2] = 0; }
  }
}

__global__ __launch_bounds__(256, 1) void fused_scan(
    const float* __restrict__ xp,
    const float* __restrict__ whh0,
    const float* __restrict__ wih1, const float* __restrict__ whh1,
    const float* __restrict__ bih1, const float* __restrict__ bhh1,
    const float* __restrict__ wih2, const float* __restrict__ whh2,
    const float* __restrict__ bih2, const float* __restrict__ bhh2,
    u64* __restrict__ rec0, u64* __restrict__ rec1, u64* __restrict__ rec2,
    float* __restrict__ hs2) {
  // wh[mat][kg*40 + r]: 8 f16 of row r, k = 8*kg..8*kg+7. mat1=hh, mat0=ih.
  __shared__ uint4 wh[2 * 3200];                    // 102,400 B
  __shared__ __align__(16) unsigned short hbufh[640];
  __shared__ __align__(16) unsigned short xbufh[640];
  __shared__ float pdot[4][40];
  const int tid = threadIdx.x;
  const int l = blockIdx.x / SB, b = blockIdx.x % SB;
  const int lane = tid & 63, wv = tid >> 6;

  const float* Wih = (l == 1) ? wih1 : wih2;
  const float* Whh = (l == 0) ? whh0 : ((l == 1) ? whh1 : whh2);
  const u64* recI = (l == 1) ? rec0 : rec1;
  u64* recO = (l == 0) ? rec0 : ((l == 1) ? rec1 : rec2);

  // stage weight slices -> LDS f16 (idx = mat*3200 + r*80 + kg: coalesced k)
  const int nstage = (l > 0) ? 6400 : 3200;
  for (int idx = tid; idx < nstage; idx += 256) {
    const int mat = idx >> 11 /*  /2048? no */ ;  // placeholder, fixed below
  }
  // (proper staging loop)
  for (int idx = tid; idx < nstage; idx += 256) {
    int rem = idx;
    const int mat = (rem < 3200) ? 1 : 0;          // stage hh first, then ih
    if (mat == 0) rem -= 3200;
    const int r = rem / 80, kg = rem - r * 80;
    const int g = r / SDP, d = r - g * SDP;
    const long grow = (long)(g * HD + b * SDP + d) * HD;
    const float* wr = ((mat == 1) ? Whh : Wih) + grow + kg * 8;
    const float4 wa = *(const float4*)(wr);
    const float4 wb = *(const float4*)(wr + 4);
    wh[mat * 3200 + kg * 40 + r] =
        make_uint4(packh(wa.x, wa.y), packh(wa.z, wa.w),
                   packh(wb.x, wb.y), packh(wb.z, wb.w));
  }

  // per-row external term in gate-wave lanes 0..39 (row = lane)
  float ext = 0.f;
  int gxi = 0;
  if (wv == GATEW && lane < 40) {
    const int g = lane / SDP, d = lane - g * SDP;
    gxi = g * HD + b * SDP + d;
    if (l == 0) {
      ext = xp[gxi];   // t = 0
    } else {
      const float* bi = (l == 1) ? bih1 : bih2;
      const float* bh = (l == 1) ? bhh1 : bhh2;
      ext = bi[gxi] + bh[gxi];
    }
  }
  __syncthreads();

  float creg = 0.f;
  for (int t = 0; t < T_SEQ; t++) {
    // ---- poll phase: w0/w2 own row (t-1); w3 upstream row (t); GATEW idle
    if (wv == 0) {
      if (t == 0) zero_row(hbufh, lane, 0, 2);
      else poll_quads(recO + (long)(t - 1) * REC64, hbufh, lane, 0, 2, (unsigned)t, b);
    } else if (wv == 2) {
      if (t == 0) zero_row(hbufh, lane, 2, 2);
      else poll_quads(recO + (long)(t - 1) * REC64, hbufh, lane, 2, 2, (unsigned)t, b);
    } else if (wv == 3 && l > 0) {
      poll_quads(recI + (long)t * REC64, xbufh, lane, 0, 4, (unsigned)(t + 1), -1);
    }
    __syncthreads();   // A: hbufh/xbufh ready

    // ---- dot phase: lane r (<40) owns row r; wave wv owns k-quarter wv
    {
      const bool act = lane < 40;
      float acc0 = 0.f, acc1 = 0.f;
      if (act) {
        const int kg0 = wv * 20;
        const uint4* wp = &wh[3200 + kg0 * 40 + lane];
        const uint4* hb = ((const uint4*)hbufh) + kg0;
#pragma unroll
        for (int g = 0; g < 20; g += 2) {
          const uint4 wA = wp[g * 40];
          const uint4 hA = hb[g];
          acc0 = dot2acc(wA.x, hA.x, acc0); acc0 = dot2acc(wA.y, hA.y, acc0);
          acc0 = dot2acc(wA.z, hA.z, acc0); acc0 = dot2acc(wA.w, hA.w, acc0);
          const uint4 wB = wp[(g + 1) * 40];
          const uint4 hB = hb[g + 1];
          acc1 = dot2acc(wB.x, hB.x, acc1); acc1 = dot2acc(wB.y, hB.y, acc1);
          acc1 = dot2acc(wB.z, hB.z, acc1); acc1 = dot2acc(wB.w, hB.w, acc1);
        }
        if (l > 0) {
          const uint4* wq = &wh[kg0 * 40 + lane];
          const uint4* xb = ((const uint4*)xbufh) + kg0;
#pragma unroll
          for (int g = 0; g < 20; g += 2) {
            const uint4 wA = wq[g * 40];
            const uint4 xA = xb[g];
            acc0 = dot2acc(wA.x, xA.x, acc0); acc0 = dot2acc(wA.y, xA.y, acc0);
            acc0 = dot2acc(wA.z, xA.z, acc0); acc0 = dot2acc(wA.w, xA.w, acc0);
            const uint4 wB = wq[(g + 1) * 40];
            const uint4 xB = xb[g + 1];
            acc1 = dot2acc(wB.x, xB.x, acc1); acc1 = dot2acc(wB.y, xB.y, acc1);
            acc1 = dot2acc(wB.z, xB.z, acc1); acc1 = dot2acc(wB.w, xB.w, acc1);
          }
        }
        pdot[wv][lane] = acc0 + acc1;
      }
    }
    __syncthreads();   // B: pdot ready

    // ---- gate phase (wave GATEW): rows distributed over lanes 0..39
    if (wv == GATEW) {
      float av = 0.f;
      if (lane < 40) {
        const float gsum = pdot[0][lane] + pdot[1][lane] + pdot[2][lane] +
                           pdot[3][lane] + ext;
        const int gate = lane / SDP;
        if (gate == 2) {   // tanh, overflow-robust
          const float e2 = __expf(2.f * gsum);
          av = 1.f - 2.f / (e2 + 1.f);
        } else {           // sigmoid
          av = 1.f / (1.f + __expf(-gsum));
        }
      }
      const float ai = av;                       // lane d: gate i at lane d
      const float af = __shfl(av, lane + SDP);
      const float ag = __shfl(av, lane + 2 * SDP);
      const float ao = __shfl(av, lane + 3 * SDP);
      float h = 0.f;
      if (lane < SDP) {
        creg = af * creg + ai * ag;
        const float e2 = __expf(2.f * creg);
        h = ao * (1.f - 2.f / (e2 + 1.f));
        hbufh[b * SDP + lane] = f2h(h);          // own slice for t+1
        if (l == 2) hs2[(long)t * HD + b * SDP + lane] = h;
      }
      // prefetch next xp (l==0) — consumed next step
      if (l == 0 && lane < 40 && t + 1 < T_SEQ)
        ext = xp[(long)(t + 1) * GD + gxi];
      // pack + publish record (lanes 0-3, one 32B coalesced store)
      const float ha = __shfl(h, 3 * lane);
      const float hb2 = __shfl(h, 3 * lane + 1);
      const float hc = __shfl(h, 3 * lane + 2);
      if (lane < 4) {
        const unsigned seq = (unsigned)(t + 1);
        const unsigned sa = f2h(ha);
        const unsigned sb = (lane < 3) ? f2h(hb2) : 0u;
        const unsigned sc = (lane < 3) ? f2h(hc) : 0u;
        const u64 val = (u64)(sa | (sb << 16)) | ((u64)(sc | (seq << 16)) << 32);
        __hip_atomic_store(recO + (long)t * REC64 + b * 4 + lane, val,
                           __ATOMIC_RELAXED, __HIP_MEMORY_SCOPE_AGENT);
      }
    }
  }
}

// ---------------------------------------------------------------------------
// GCN pieces
// ---------------------------------------------------------------------------
__global__ __launch_bounds__(256) void gcn_gemm(
    const float* __restrict__ X, const float* __restrict__ W,
    float* __restrict__ Y, int di, int dout) {
  __shared__ float xr[640];
  const int n = blockIdx.x;
  for (int k = threadIdx.x; k < di; k += 256) xr[k] = X[(long)n * di + k];
  __syncthreads();
  for (int c = threadIdx.x; c < dout; c += 256) {
    float acc = 0.f;
    for (int k = 0; k < di; k++) acc = fmaf(xr[k], W[(long)k * dout + c], acc);
    Y[(long)n * dout + c] = acc;
  }
}

__global__ void deg_kernel(const int* __restrict__ dst, unsigned int* __restrict__ deg) {
  const int e = blockIdx.x * 256 + threadIdx.x;
  if (e < NEDGE) atomicAdd(&deg[dst[e]], 1u);
}

__global__ void dinv_kernel(const unsigned int* __restrict__ deg, float* __restrict__ dinv) {
  const int n = blockIdx.x * 256 + threadIdx.x;
  if (n < NNODES) dinv[n] = 1.f / sqrtf((float)(deg[n] + 1u));
}

__global__ __launch_bounds__(128) void gcn_scatter(
    const float* __restrict__ XW, const int* __restrict__ src,
    const int* __restrict__ dst, const float* __restrict__ dinv,
    float* __restrict__ out, int dout) {
  const int e = blockIdx.x;
  const int s = src[e], d = dst[e];
  const float nrm = dinv[s] * dinv[d];
  for (int c = threadIdx.x; c < dout; c += 128)
    atomicAdd(&out[(long)d * dout + c], XW[(long)s * dout + c] * nrm);
}

__global__ __launch_bounds__(256) void gcn_bn(
    const float* __restrict__ scat, const float* __restrict__ xw,
    const float* __restrict__ dinv, const float* __restrict__ bias,
    float* __restrict__ out, int dout) {
  const int c = blockIdx.x;
  const float bc = bias[c];
  float s = 0.f, s2 = 0.f;
  for (int n = threadIdx.x; n < NNODES; n += 256) {
    float v = scat[(long)n * dout + c] + xw[(long)n * dout + c] * dinv[n] * dinv[n] + bc;
    v = v >= 0.f ? v : 0.01f * v;
    s += v; s2 += v * v;
  }
  __shared__ float rs[4], rs2[4];
#pragma unroll
  for (int off = 32; off; off >>= 1) { s += __shfl_down(s, off, 64); s2 += __shfl_down(s2, off, 64); }
  const int w = threadIdx.x >> 6;
  if ((threadIdx.x & 63) == 0) { rs[w] = s; rs2[w] = s2; }
  __syncthreads();
  const float ts  = rs[0] + rs[1] + rs[2] + rs[3];
  const float ts2 = rs2[0] + rs2[1] + rs2[2] + rs2[3];
  const float mu = ts * (1.f / (float)NNODES);
  const float var = ts2 * (1.f / (float)NNODES) - mu * mu;
  const float rstd = 1.f / sqrtf(var + 1e-5f);
  for (int n = threadIdx.x; n < NNODES; n += 256) {
    float v = scat[(long)n * dout + c] + xw[(long)n * dout + c] * dinv[n] * dinv[n] + bc;
    v = v >= 0.f ? v : 0.01f * v;
    out[(long)n * dout + c] = (v - mu) * rstd;
  }
}

__global__ __launch_bounds__(64) void pool_kernel(
    const float* __restrict__ x, float* __restrict__ emb, float* __restrict__ dout) {
  const int g = blockIdx.x, c = threadIdx.x;
  if (c >= 50) return;
  float s = 0.f;
  for (int r = 0; r < 128; r++) s += x[(long)(g * 128 + r) * 50 + c];
  emb[g * 50 + c] = s;
  dout[16 + g * 50 + c] = s;
}

__global__ __launch_bounds__(64) void fc_head(
    const float* __restrict__ emb,
    const float* __restrict__ w1, const float* __restrict__ b1,
    const float* __restrict__ w2, const float* __restrict__ b2,
    const float* __restrict__ w3, const float* __restrict__ b3,
    float* __restrict__ dout) {
  const int g = threadIdx.x;
  if (g >= NGRAPH) return;
  float e[50];
#pragma unroll
  for (int k = 0; k < 50; k++) e[k] = emb[g * 50 + k];
  float t1[32];
  for (int j = 0; j < 32; j++) {
    float a = b1[j];
    for (int k = 0; k < 50; k++) a = fmaf(e[k], w1[k * 32 + j], a);
    t1[j] = a;
  }
  float t2[16];
  for (int j = 0; j < 16; j++) {
    float a = b2[j];
    for (int k = 0; k < 32; k++) a = fmaf(t1[k], w2[k * 16 + j], a);
    t2[j] = a;
  }
  float y = b3[0];
  for (int k = 0; k < 16; k++) y = fmaf(t2[k], w3[k], y);
  dout[g] = y;
}

// ---------------------------------------------------------------------------
extern "C" void kernel_launch(void* const* d_in, const int* in_sizes, int n_in,
                              void* d_out, int out_size, void* d_ws, size_t ws_size,
                              hipStream_t stream) {
  const float* x_in  = (const float*)d_in[0];
  const int*   eidx  = (const int*)d_in[1];
  const float* w_ih[3] = {(const float*)d_in[2], (const float*)d_in[6],  (const float*)d_in[10]};
  const float* w_hh[3] = {(const float*)d_in[3], (const float*)d_in[7],  (const float*)d_in[11]};
  const float* b_ih[3] = {(const float*)d_in[4], (const float*)d_in[8],  (const float*)d_in[12]};
  const float* b_hh[3] = {(const float*)d_in[5], (const float*)d_in[9],  (const float*)d_in[13]};
  const float* gw[4] = {(const float*)d_in[14], (const float*)d_in[16], (const float*)d_in[18], (const float*)d_in[20]};
  const float* gbv[4] = {(const float*)d_in[15], (const float*)d_in[17], (const float*)d_in[19], (const float*)d_in[21]};
  const float* fw1 = (const float*)d_in[22]; const float* fb1 = (const float*)d_in[23];
  const float* fw2 = (const float*)d_in[24]; const float* fb2 = (const float*)d_in[25];
  const float* fw3 = (const float*)d_in[26]; const float* fb3 = (const float*)d_in[27];
  const int* src = eidx;
  const int* dst = eidx + NEDGE;

  // workspace layout
  float* ws  = (float*)d_ws;
  float* xp  = ws;                                  // 5,242,880 f
  u64* rec0 = (u64*)(ws + 5242880);                 // 524,288 u64 each
  u64* rec1 = rec0 + 524288;
  u64* rec2 = rec1 + 524288;
  float* hs2 = ws + 5242880 + 3145728;              // 1,310,720 f
  unsigned int* deg = (unsigned int*)(hs2 + 1310720);
  float* dinv = (float*)(deg + 2048);
  float* emb  = dinv + 2048;
  // GCN buffers alias the (then-dead) xp region
  float* ga = xp;
  float* gb = xp + 655360;
  float* x0 = xp + 1310720;
  float* x1 = xp + 1966080;

  // seq=0 in all records (expected seqs are >=1); zero deg
  hipMemsetAsync(rec0, 0, (size_t)3 * 524288 * sizeof(u64), stream);
  hipMemsetAsync(deg, 0, 2048 * sizeof(unsigned int), stream);

  gemm_abt<<<dim3(GD / 64, NNODES / 64), 256, 0, stream>>>(
      x_in, w_ih[0], b_ih[0], b_hh[0], xp, NNODES, GD, KIN);

  deg_kernel<<<NEDGE / 256, 256, 0, stream>>>(dst, deg);
  dinv_kernel<<<NNODES / 256, 256, 0, stream>>>(deg, dinv);

  fused_scan<<<3 * SB, 256, 0, stream>>>(
      xp, w_hh[0], w_ih[1], w_hh[1], b_ih[1], b_hh[1],
      w_ih[2], w_hh[2], b_ih[2], b_hh[2], rec0, rec1, rec2, hs2);

  const int dims_in[4]  = {640, 320, 180, 90};
  const int dims_out[4] = {320, 180, 90, 50};
  const float* xin_l[4] = {hs2, x0, x1, x0};
  float* xout_l[4]      = {x0, x1, x0, x1};
  for (int l = 0; l < 4; l++) {
    gcn_gemm<<<NNODES, 256, 0, stream>>>(xin_l[l], gw[l], ga, dims_in[l], dims_out[l]);
    hipMemsetAsync(gb, 0, (size_t)NNODES * dims_out[l] * sizeof(float), stream);
    gcn_scatter<<<NEDGE, 128, 0, stream>>>(ga, src, dst, dinv, gb, dims_out[l]);
    gcn_bn<<<dims_out[l], 256, 0, stream>>>(gb, ga, dinv, gbv[l], xout_l[l], dims_out[l]);
  }

  pool_kernel<<<NGRAPH, 64, 0, stream>>>(x1, emb, (float*)d_out);
  fc_head<<<1, 64, 0, stream>>>(emb, fw1, fb1, fw2, fb2, fw3, fb3, (float*)d_out);
}

// Round 6
// 6700.998 us; speedup vs baseline: 2.1349x; 1.2086x over previous
//
#include <hip/hip_runtime.h>
#include <stdint.h>

#define NNODES 2048
#define T_SEQ  2048
#define HD     640
#define GD     2560   // 4*HD
#define KIN    8500
#define NEDGE  65536
#define NGRAPH 16
#define SB     64     // blocks per layer
#define SDP    10     // h-dims per block
#define REC64  256    // u64 per timestep row: 64 records x 4 parts

typedef unsigned long long u64;
typedef _Float16 half2v __attribute__((ext_vector_type(2)));
using short8 = __attribute__((ext_vector_type(8))) short;
using f32x4  = __attribute__((ext_vector_type(4))) float;

#if __has_builtin(__builtin_amdgcn_fdot2)
#define HAVE_FDOT2 1
#endif

__device__ __forceinline__ float dot2acc(unsigned w, unsigned h, float acc) {
#ifdef HAVE_FDOT2
  return __builtin_amdgcn_fdot2(__builtin_bit_cast(half2v, w),
                                __builtin_bit_cast(half2v, h), acc, false);
#else
  acc += (float)__builtin_bit_cast(_Float16, (unsigned short)(w & 0xffffu)) *
         (float)__builtin_bit_cast(_Float16, (unsigned short)(h & 0xffffu));
  acc += (float)__builtin_bit_cast(_Float16, (unsigned short)(w >> 16)) *
         (float)__builtin_bit_cast(_Float16, (unsigned short)(h >> 16));
  return acc;
#endif
}

__device__ __forceinline__ unsigned short f2h(float x) {
  return __builtin_bit_cast(unsigned short, (_Float16)x);
}
__device__ __forceinline__ unsigned packh(float a, float b) {
  return (unsigned)f2h(a) | ((unsigned)f2h(b) << 16);
}
__device__ __forceinline__ unsigned f2bf(float x) {
  unsigned u = __float_as_uint(x);
  return (u + 0x7fffu + ((u >> 16) & 1u)) >> 16;
}
__device__ __forceinline__ unsigned packbf(float a, float b) {
  return f2bf(a) | (f2bf(b) << 16);
}

// ---------------------------------------------------------------------------
// C[M,N] = A[M,K] @ W[N,K]^T + b1[n] + b2[n], bf16 MFMA 16x16x32.
// Block 256 thr = 4 waves; block tile 128x128; wave tile 64x64 (4x4 frags).
// LDS rows padded to 40 shorts (80 B) for conflict-light b128 frag reads.
// ---------------------------------------------------------------------------
#define GK 32
__global__ __launch_bounds__(256) void gemm_mfma(
    const float* __restrict__ A, const float* __restrict__ W,
    const float* __restrict__ b1, const float* __restrict__ b2,
    float* __restrict__ C, int M, int N, int K) {
  __shared__ __align__(16) short As[128 * 40];
  __shared__ __align__(16) short Ws[128 * 40];
  const int tid = threadIdx.x;
  const int wave = tid >> 6, lane = tid & 63;
  const int bm = blockIdx.y * 128, bn = blockIdx.x * 128;
  const int wm = (wave >> 1) * 64, wn = (wave & 1) * 64;
  const int mrow = lane & 15, quad = lane >> 4;
  const int srow = tid >> 1, skc = (tid & 1) * 16;   // staging: 16 k per thread
  f32x4 acc[4][4] = {};
  for (int k0 = 0; k0 < K; k0 += GK) {
    // ---- stage A,W tiles (fp32 -> bf16)
    float av[16], wv[16];
    if (k0 + GK <= K) {
      const float* Ap = A + (long)(bm + srow) * K + k0 + skc;
      const float* Wp = W + (long)(bn + srow) * K + k0 + skc;
#pragma unroll
      for (int i = 0; i < 4; i++) {
        float4 a4 = *(const float4*)(Ap + 4 * i);
        float4 w4 = *(const float4*)(Wp + 4 * i);
        av[4*i]=a4.x; av[4*i+1]=a4.y; av[4*i+2]=a4.z; av[4*i+3]=a4.w;
        wv[4*i]=w4.x; wv[4*i+1]=w4.y; wv[4*i+2]=w4.z; wv[4*i+3]=w4.w;
      }
    } else {
#pragma unroll
      for (int i = 0; i < 16; i++) {
        const int k = k0 + skc + i;
        av[i] = (k < K) ? A[(long)(bm + srow) * K + k] : 0.f;
        wv[i] = (k < K) ? W[(long)(bn + srow) * K + k] : 0.f;
      }
    }
    __syncthreads();
    {
      uint4* pa = (uint4*)&As[srow * 40 + skc];
      uint4* pw = (uint4*)&Ws[srow * 40 + skc];
      pa[0] = make_uint4(packbf(av[0],av[1]), packbf(av[2],av[3]),
                         packbf(av[4],av[5]), packbf(av[6],av[7]));
      pa[1] = make_uint4(packbf(av[8],av[9]), packbf(av[10],av[11]),
                         packbf(av[12],av[13]), packbf(av[14],av[15]));
      pw[0] = make_uint4(packbf(wv[0],wv[1]), packbf(wv[2],wv[3]),
                         packbf(wv[4],wv[5]), packbf(wv[6],wv[7]));
      pw[1] = make_uint4(packbf(wv[8],wv[9]), packbf(wv[10],wv[11]),
                         packbf(wv[12],wv[13]), packbf(wv[14],wv[15]));
    }
    __syncthreads();
    // ---- frags + mfma
    short8 af[4], bf[4];
#pragma unroll
    for (int mi = 0; mi < 4; mi++)
      af[mi] = *(const short8*)&As[(wm + mi * 16 + mrow) * 40 + quad * 8];
#pragma unroll
    for (int ni = 0; ni < 4; ni++)
      bf[ni] = *(const short8*)&Ws[(wn + ni * 16 + mrow) * 40 + quad * 8];
#pragma unroll
    for (int mi = 0; mi < 4; mi++)
#pragma unroll
      for (int ni = 0; ni < 4; ni++)
        acc[mi][ni] = __builtin_amdgcn_mfma_f32_16x16x32_bf16(
            af[mi], bf[ni], acc[mi][ni], 0, 0, 0);
  }
  // ---- epilogue: C/D layout col=lane&15, row=quad*4+reg
#pragma unroll
  for (int ni = 0; ni < 4; ni++) {
    const int c = bn + wn + ni * 16 + mrow;
    const float bias = b1[c] + b2[c];
#pragma unroll
    for (int mi = 0; mi < 4; mi++) {
      const int r0 = bm + wm + mi * 16 + quad * 4;
#pragma unroll
      for (int reg = 0; reg < 4; reg++)
        C[(long)(r0 + reg) * N + c] = acc[mi][ni][reg] + bias;
    }
  }
}

// ---------------------------------------------------------------------------
// Fused 3-layer pipelined LSTM scan — per-wave poll+dot fusion, 1 barrier.
// Wave w owns k-slice [w*160, w*160+160) = records [w*16, w*16+16).
// Lane polls 1 u64 (record rid=w*16+(lane>>2), part j=lane&3); unpacks into
// its wave-private LDS region; threadfence_block; dot; pdot[parity][w][r].
// ---------------------------------------------------------------------------
__global__ __launch_bounds__(256, 1) void fused_scan(
    const float* __restrict__ xp,
    const float* __restrict__ whh0,
    const float* __restrict__ wih1, const float* __restrict__ whh1,
    const float* __restrict__ bih1, const float* __restrict__ bhh1,
    const float* __restrict__ wih2, const float* __restrict__ whh2,
    const float* __restrict__ bih2, const float* __restrict__ bhh2,
    u64* __restrict__ rec0, u64* __restrict__ rec1, u64* __restrict__ rec2,
    float* __restrict__ hs2) {
  // wh[mat][kg*40 + r]: 8 f16 of row r, k-group kg (8 f16). mat1=hh, mat0=ih.
  __shared__ uint4 wh[2 * 3200];                    // 102,400 B
  __shared__ __align__(16) unsigned short hbufh[640];
  __shared__ __align__(16) unsigned short xbufh[640];
  __shared__ float pdot[2][4][40];
  const int tid = threadIdx.x;
  const int l = blockIdx.x / SB, b = blockIdx.x % SB;
  const int lane = tid & 63, wv = tid >> 6;

  const float* Wih = (l == 1) ? wih1 : wih2;
  const float* Whh = (l == 0) ? whh0 : ((l == 1) ? whh1 : whh2);
  const u64* recI = (l == 1) ? rec0 : rec1;
  u64* recO = (l == 0) ? rec0 : ((l == 1) ? rec1 : rec2);

  // stage weight slices -> LDS f16
  const int nstage = (l > 0) ? 6400 : 3200;
  for (int idx = tid; idx < nstage; idx += 256) {
    int rem = idx;
    const int mat = (rem < 3200) ? 1 : 0;          // hh first, then ih
    if (mat == 0) rem -= 3200;
    const int r = rem / 80, kg = rem - r * 80;
    const int g = r / SDP, d = r - g * SDP;
    const long grow = (long)(g * HD + b * SDP + d) * HD;
    const float* wr = ((mat == 1) ? Whh : Wih) + grow + kg * 8;
    const float4 wa = *(const float4*)(wr);
    const float4 wb = *(const float4*)(wr + 4);
    wh[mat * 3200 + kg * 40 + r] =
        make_uint4(packh(wa.x, wa.y), packh(wa.z, wa.w),
                   packh(wb.x, wb.y), packh(wb.z, wb.w));
  }

  // gate-wave (wave 0) external term: xp row (l==0) or bias sum (l>0)
  float ext = 0.f;
  int gxi = 0;
  if (wv == 0 && lane < 40) {
    const int g = lane / SDP, d = lane - g * SDP;
    gxi = g * HD + b * SDP + d;
    if (l == 0) {
      ext = xp[gxi];   // t = 0
    } else {
      const float* bi = (l == 1) ? bih1 : bih2;
      const float* bh = (l == 1) ? bhh1 : bhh2;
      ext = bi[gxi] + bh[gxi];
    }
  }
  __syncthreads();

  // per-lane poll geometry
  const int rid = wv * 16 + (lane >> 2), j = lane & 3;
  const int ubase = rid * SDP + 3 * j;              // unpack base in h index
  unsigned short* hslot = hbufh + ubase;
  unsigned short* xslot = xbufh + ubase;

  float creg = 0.f;
  for (int t = 0; t < T_SEQ; t++) {
    // ---- fused poll+unpack (own-layer t-1, upstream t)
    unsigned pend = ((t > 0) ? 1u : 0u) | ((l > 0) ? 2u : 0u);
    const long io = (long)(t - 1) * REC64 + wv * 64 + lane;
    const long iu = (long)t * REC64 + wv * 64 + lane;
    long spins = 0;
    u64 vo = 0, vu = 0;
    while (__any(pend != 0)) {
      if (pend & 1u) vo = __hip_atomic_load(recO + io, __ATOMIC_RELAXED,
                                            __HIP_MEMORY_SCOPE_AGENT);
      if (pend & 2u) vu = __hip_atomic_load(recI + iu, __ATOMIC_RELAXED,
                                            __HIP_MEMORY_SCOPE_AGENT);
      if ((pend & 1u) && (unsigned)(vo >> 48) == (unsigned)t) {
        pend &= ~1u;
        const unsigned lo = (unsigned)vo, hi = (unsigned)(vo >> 32);
        hslot[0] = (unsigned short)lo;
        if (j < 3) { hslot[1] = (unsigned short)(lo >> 16);
                     hslot[2] = (unsigned short)hi; }
      }
      if ((pend & 2u) && (unsigned)(vu >> 48) == (unsigned)(t + 1)) {
        pend &= ~2u;
        const unsigned lo = (unsigned)vu, hi = (unsigned)(vu >> 32);
        xslot[0] = (unsigned short)lo;
        if (j < 3) { xslot[1] = (unsigned short)(lo >> 16);
                     xslot[2] = (unsigned short)hi; }
      }
      if (__any(pend != 0)) {
        if (++spins > 30000000L) break;  // safety: wrong > hung
        __builtin_amdgcn_s_sleep(1);
      }
    }
    if (t == 0) {   // zero own h slice
      hslot[0] = 0;
      if (j < 3) { hslot[1] = 0; hslot[2] = 0; }
    }
    __threadfence_block();   // order unpack writes before same-wave reads

    // ---- dot: lane r (<40) owns row r over this wave's k-slice
    if (lane < 40) {
      const int kg0 = wv * 20;
      float acc0 = 0.f, acc1 = 0.f;
      const uint4* wp = &wh[3200 + kg0 * 40 + lane];
      const uint4* hb = ((const uint4*)hbufh) + kg0;
#pragma unroll
      for (int g = 0; g < 20; g += 2) {
        const uint4 wA = wp[g * 40];
        const uint4 hA = hb[g];
        acc0 = dot2acc(wA.x, hA.x, acc0); acc0 = dot2acc(wA.y, hA.y, acc0);
        acc0 = dot2acc(wA.z, hA.z, acc0); acc0 = dot2acc(wA.w, hA.w, acc0);
        const uint4 wB = wp[(g + 1) * 40];
        const uint4 hB = hb[g + 1];
        acc1 = dot2acc(wB.x, hB.x, acc1); acc1 = dot2acc(wB.y, hB.y, acc1);
        acc1 = dot2acc(wB.z, hB.z, acc1); acc1 = dot2acc(wB.w, hB.w, acc1);
      }
      if (l > 0) {
        const uint4* wq = &wh[kg0 * 40 + lane];
        const uint4* xb = ((const uint4*)xbufh) + kg0;
#pragma unroll
        for (int g = 0; g < 20; g += 2) {
          const uint4 wA = wq[g * 40];
          const uint4 xA = xb[g];
          acc0 = dot2acc(wA.x, xA.x, acc0); acc0 = dot2acc(wA.y, xA.y, acc0);
          acc0 = dot2acc(wA.z, xA.z, acc0); acc0 = dot2acc(wA.w, xA.w, acc0);
          const uint4 wB = wq[(g + 1) * 40];
          const uint4 xB = xb[g + 1];
          acc1 = dot2acc(wB.x, xB.x, acc1); acc1 = dot2acc(wB.y, xB.y, acc1);
          acc1 = dot2acc(wB.z, xB.z, acc1); acc1 = dot2acc(wB.w, xB.w, acc1);
        }
      }
      pdot[t & 1][wv][lane] = acc0 + acc1;
    }
    __syncthreads();   // single barrier: pdot ready

    // ---- gate phase (wave 0); no trailing barrier (pdot parity-buffered)
    if (wv == 0) {
      const int par = t & 1;
      float av = 0.f;
      if (lane < 40) {
        const float gsum = pdot[par][0][lane] + pdot[par][1][lane] +
                           pdot[par][2][lane] + pdot[par][3][lane] + ext;
        if (lane / SDP == 2) {        // tanh (g gate)
          const float e2 = __expf(2.f * gsum);
          av = 1.f - 2.f / (e2 + 1.f);
        } else {                      // sigmoid
          av = 1.f / (1.f + __expf(-gsum));
        }
      }
      const float ai = av;
      const float af = __shfl(av, lane + SDP);
      const float ag = __shfl(av, lane + 2 * SDP);
      const float ao = __shfl(av, lane + 3 * SDP);
      float h = 0.f;
      if (lane < SDP) {
        creg = af * creg + ai * ag;
        const float e2 = __expf(2.f * creg);
        h = ao * (1.f - 2.f / (e2 + 1.f));
        if (l == 2) hs2[(long)t * HD + b * SDP + lane] = h;
      }
      if (l == 0 && lane < 40 && t + 1 < T_SEQ)
        ext = xp[(long)(t + 1) * GD + gxi];          // prefetch next step
      const float ha = __shfl(h, 3 * lane);
      const float hb2 = __shfl(h, 3 * lane + 1);
      const float hc = __shfl(h, 3 * lane + 2);
      if (lane < 4) {
        const unsigned seq = (unsigned)(t + 1);
        const unsigned sa = f2h(ha);
        const unsigned sb = (lane < 3) ? f2h(hb2) : 0u;
        const unsigned sc = (lane < 3) ? f2h(hc) : 0u;
        const u64 val = (u64)(sa | (sb << 16)) | ((u64)(sc | (seq << 16)) << 32);
        __hip_atomic_store(recO + (long)t * REC64 + b * 4 + lane, val,
                           __ATOMIC_RELAXED, __HIP_MEMORY_SCOPE_AGENT);
      }
    }
  }
}

// ---------------------------------------------------------------------------
// GCN pieces
// ---------------------------------------------------------------------------
__global__ __launch_bounds__(256) void gcn_gemm(
    const float* __restrict__ X, const float* __restrict__ W,
    float* __restrict__ Y, int di, int dout) {
  __shared__ float xr[640];
  const int n = blockIdx.x;
  for (int k = threadIdx.x; k < di; k += 256) xr[k] = X[(long)n * di + k];
  __syncthreads();
  for (int c = threadIdx.x; c < dout; c += 256) {
    float acc = 0.f;
    for (int k = 0; k < di; k++) acc = fmaf(xr[k], W[(long)k * dout + c], acc);
    Y[(long)n * dout + c] = acc;
  }
}

__global__ void deg_kernel(const int* __restrict__ dst, unsigned int* __restrict__ deg) {
  const int e = blockIdx.x * 256 + threadIdx.x;
  if (e < NEDGE) atomicAdd(&deg[dst[e]], 1u);
}

__global__ void dinv_kernel(const unsigned int* __restrict__ deg, float* __restrict__ dinv) {
  const int n = blockIdx.x * 256 + threadIdx.x;
  if (n < NNODES) dinv[n] = 1.f / sqrtf((float)(deg[n] + 1u));
}

__global__ __launch_bounds__(128) void gcn_scatter(
    const float* __restrict__ XW, const int* __restrict__ src,
    const int* __restrict__ dst, const float* __restrict__ dinv,
    float* __restrict__ out, int dout) {
  const int e = blockIdx.x;
  const int s = src[e], d = dst[e];
  const float nrm = dinv[s] * dinv[d];
  for (int c = threadIdx.x; c < dout; c += 128)
    atomicAdd(&out[(long)d * dout + c], XW[(long)s * dout + c] * nrm);
}

__global__ __launch_bounds__(256) void gcn_bn(
    const float* __restrict__ scat, const float* __restrict__ xw,
    const float* __restrict__ dinv, const float* __restrict__ bias,
    float* __restrict__ out, int dout) {
  const int c = blockIdx.x;
  const float bc = bias[c];
  float s = 0.f, s2 = 0.f;
  for (int n = threadIdx.x; n < NNODES; n += 256) {
    float v = scat[(long)n * dout + c] + xw[(long)n * dout + c] * dinv[n] * dinv[n] + bc;
    v = v >= 0.f ? v : 0.01f * v;
    s += v; s2 += v * v;
  }
  __shared__ float rs[4], rs2[4];
#pragma unroll
  for (int off = 32; off; off >>= 1) { s += __shfl_down(s, off, 64); s2 += __shfl_down(s2, off, 64); }
  const int w = threadIdx.x >> 6;
  if ((threadIdx.x & 63) == 0) { rs[w] = s; rs2[w] = s2; }
  __syncthreads();
  const float ts  = rs[0] + rs[1] + rs[2] + rs[3];
  const float ts2 = rs2[0] + rs2[1] + rs2[2] + rs2[3];
  const float mu = ts * (1.f / (float)NNODES);
  const float var = ts2 * (1.f / (float)NNODES) - mu * mu;
  const float rstd = 1.f / sqrtf(var + 1e-5f);
  for (int n = threadIdx.x; n < NNODES; n += 256) {
    float v = scat[(long)n * dout + c] + xw[(long)n * dout + c] * dinv[n] * dinv[n] + bc;
    v = v >= 0.f ? v : 0.01f * v;
    out[(long)n * dout + c] = (v - mu) * rstd;
  }
}

__global__ __launch_bounds__(64) void pool_kernel(
    const float* __restrict__ x, float* __restrict__ emb, float* __restrict__ dout) {
  const int g = blockIdx.x, c = threadIdx.x;
  if (c >= 50) return;
  float s = 0.f;
  for (int r = 0; r < 128; r++) s += x[(long)(g * 128 + r) * 50 + c];
  emb[g * 50 + c] = s;
  dout[16 + g * 50 + c] = s;
}

__global__ __launch_bounds__(64) void fc_head(
    const float* __restrict__ emb,
    const float* __restrict__ w1, const float* __restrict__ b1,
    const float* __restrict__ w2, const float* __restrict__ b2,
    const float* __restrict__ w3, const float* __restrict__ b3,
    float* __restrict__ dout) {
  const int g = threadIdx.x;
  if (g >= NGRAPH) return;
  float e[50];
#pragma unroll
  for (int k = 0; k < 50; k++) e[k] = emb[g * 50 + k];
  float t1[32];
  for (int j = 0; j < 32; j++) {
    float a = b1[j];
    for (int k = 0; k < 50; k++) a = fmaf(e[k], w1[k * 32 + j], a);
    t1[j] = a;
  }
  float t2[16];
  for (int j = 0; j < 16; j++) {
    float a = b2[j];
    for (int k = 0; k < 32; k++) a = fmaf(t1[k], w2[k * 16 + j], a);
    t2[j] = a;
  }
  float y = b3[0];
  for (int k = 0; k < 16; k++) y = fmaf(t2[k], w3[k], y);
  dout[g] = y;
}

// ---------------------------------------------------------------------------
extern "C" void kernel_launch(void* const* d_in, const int* in_sizes, int n_in,
                              void* d_out, int out_size, void* d_ws, size_t ws_size,
                              hipStream_t stream) {
  const float* x_in  = (const float*)d_in[0];
  const int*   eidx  = (const int*)d_in[1];
  const float* w_ih[3] = {(const float*)d_in[2], (const float*)d_in[6],  (const float*)d_in[10]};
  const float* w_hh[3] = {(const float*)d_in[3], (const float*)d_in[7],  (const float*)d_in[11]};
  const float* b_ih[3] = {(const float*)d_in[4], (const float*)d_in[8],  (const float*)d_in[12]};
  const float* b_hh[3] = {(const float*)d_in[5], (const float*)d_in[9],  (const float*)d_in[13]};
  const float* gw[4] = {(const float*)d_in[14], (const float*)d_in[16], (const float*)d_in[18], (const float*)d_in[20]};
  const float* gbv[4] = {(const float*)d_in[15], (const float*)d_in[17], (const float*)d_in[19], (const float*)d_in[21]};
  const float* fw1 = (const float*)d_in[22]; const float* fb1 = (const float*)d_in[23];
  const float* fw2 = (const float*)d_in[24]; const float* fb2 = (const float*)d_in[25];
  const float* fw3 = (const float*)d_in[26]; const float* fb3 = (const float*)d_in[27];
  const int* src = eidx;
  const int* dst = eidx + NEDGE;

  // workspace layout
  float* ws  = (float*)d_ws;
  float* xp  = ws;                                  // 5,242,880 f
  u64* rec0 = (u64*)(ws + 5242880);                 // 524,288 u64 each
  u64* rec1 = rec0 + 524288;
  u64* rec2 = rec1 + 524288;
  float* hs2 = ws + 5242880 + 3145728;              // 1,310,720 f
  unsigned int* deg = (unsigned int*)(hs2 + 1310720);
  float* dinv = (float*)(deg + 2048);
  float* emb  = dinv + 2048;
  // GCN buffers alias the (then-dead) xp region
  float* ga = xp;
  float* gb = xp + 655360;
  float* x0 = xp + 1310720;
  float* x1 = xp + 1966080;

  // seq=0 in all records (expected seqs are >=1); zero deg
  hipMemsetAsync(rec0, 0, (size_t)3 * 524288 * sizeof(u64), stream);
  hipMemsetAsync(deg, 0, 2048 * sizeof(unsigned int), stream);

  gemm_mfma<<<dim3(GD / 128, NNODES / 128), 256, 0, stream>>>(
      x_in, w_ih[0], b_ih[0], b_hh[0], xp, NNODES, GD, KIN);

  deg_kernel<<<NEDGE / 256, 256, 0, stream>>>(dst, deg);
  dinv_kernel<<<NNODES / 256, 256, 0, stream>>>(deg, dinv);

  fused_scan<<<3 * SB, 256, 0, stream>>>(
      xp, w_hh[0], w_ih[1], w_hh[1], b_ih[1], b_hh[1],
      w_ih[2], w_hh[2], b_ih[2], b_hh[2], rec0, rec1, rec2, hs2);

  const int dims_in[4]  = {640, 320, 180, 90};
  const int dims_out[4] = {320, 180, 90, 50};
  const float* xin_l[4] = {hs2, x0, x1, x0};
  float* xout_l[4]      = {x0, x1, x0, x1};
  for (int l = 0; l < 4; l++) {
    gcn_gemm<<<NNODES, 256, 0, stream>>>(xin_l[l], gw[l], ga, dims_in[l], dims_out[l]);
    hipMemsetAsync(gb, 0, (size_t)NNODES * dims_out[l] * sizeof(float), stream);
    gcn_scatter<<<NEDGE, 128, 0, stream>>>(ga, src, dst, dinv, gb, dims_out[l]);
    gcn_bn<<<dims_out[l], 256, 0, stream>>>(gb, ga, dinv, gbv[l], xout_l[l], dims_out[l]);
  }

  pool_kernel<<<NGRAPH, 64, 0, stream>>>(x1, emb, (float*)d_out);
  fc_head<<<1, 64, 0, stream>>>(emb, fw1, fb1, fw2, fb2, fw3, fb3, (float*)d_out);
}